// Round 22
// baseline (201.086 us; speedup 1.0000x reference)
//
#include <hip/hip_runtime.h>

#define INFV 1e8f
#define LN2F 0.69314718055994530942f
#define L2EF 1.44269504088896340736f

constexpr int NC = 512;   // DP columns
constexpr int RW = 128;   // rows per wave
constexpr int NW = 4;     // waves per block
constexpr int NP = 10;    // panels resident in ring (was 9)
constexpr int RC = 80;    // ring columns = 10 panels of 8
constexpr int GOFF = 10;  // wave offset in groups (full-slack for tail prefetch)
constexpr int NGRP = 72 + 3 * GOFF;  // 102

// R19 host (NW=4, 2 rows/lane, salt-free ring, fast/slow path, log-domain
// interface, per-lane E) + working group-boundary pipeline:
//  - ring is bf16 (R15-proven: absmax stayed 2.0) -> 10 panels fit (80 KB).
//    With 10 panels, panel_write(h+1)'s slot (= panel h-9's) is flushed at
//    group h-1, so panel_write moves to GROUP START: its exp+ds_write chain
//    overlaps the whole compute phase (R21's serialization bug is gone).
//  - tail prefetch (mailbox spin+read, pd reads for h+1) now hits
//    long-completed writes -> group-start LDS waits leave the critical path.
//  - compute ring ops: 1x b32 read + 1x b32 write per phase (packed bf16
//    row-pair), replacing b64s.
// Publish arithmetic (GOFF=10): producer has cnt = 8h+24 >= need 8h+16 one
// full group before the consumer's tail prefetch of group h+1. Mailbox and
// all DP state stay f32; only ring traffic quantizes.
static __device__ __forceinline__ float wave_shr1(float v, float old) {
    // lanes 1..63 <- lane-1's v; lane 0 keeps `old` (bound_ctrl=false)
    return __int_as_float(__builtin_amdgcn_update_dpp(
        __float_as_int(old), __float_as_int(v), 0x138, 0xF, 0xF, false));
}
static __device__ __forceinline__ unsigned bf16rn(float x) {  // f32->bf16 RNE
    const unsigned t = __float_as_uint(x);
    return (t + 0x7FFFu + ((t >> 16) & 1u)) >> 16;
}
static __device__ __forceinline__ float bf16lo(unsigned v) { return __uint_as_float(v << 16); }
static __device__ __forceinline__ float bf16hi(unsigned v) { return __uint_as_float(v & 0xFFFF0000u); }

__global__ __launch_bounds__(256, 1) void sdtw17(const float* __restrict__ D,
                                                 float* __restrict__ O) {
    __shared__ __align__(16) unsigned short ring[NW * RC * RW];  // 81920 B bf16
    __shared__ __align__(16) float mbox[3 * NC];                 // 6144 B f32
    __shared__ int pflag[4];

    const int tid = threadIdx.x;
    const int w = tid >> 6, l = tid & 63;
    const int b = blockIdx.x;

    if (tid < 4) pflag[tid] = 0;
    __syncthreads();  // once; no barriers in the loop

    const float* __restrict__ Dg = D + (size_t)b * NC * 512 + (size_t)w * RW * NC;
    float* __restrict__ Og = O + (size_t)b * NC * 512 + (size_t)w * RW * NC;
    unsigned short* __restrict__ rg = ring + w * RC * RW;  // ushort view
    unsigned* __restrict__ rgU = (unsigned*)rg;            // u32 view (row pairs)

    // panel helpers: 128 rows x 8 cols; f = k*64+l, y = f>>1, q = f&1.
    float4 st[4];
    auto panel_load = [&](int p) {
#pragma unroll
        for (int k = 0; k < 4; ++k) {
            const int f = k * 64 + l, y = f >> 1, q = f & 1;
            st[k] = *(const float4*)(Dg + (size_t)y * NC + p * 8 + q * 4);
        }
    };
    auto panel_write = [&](int p) {  // stores bf16(e^{-D})
        const int spb = (p * 8) % RC;  // one mod per call
#pragma unroll
        for (int k = 0; k < 4; ++k) {
            const int f = k * 64 + l, y = f >> 1, q = f & 1;
#pragma unroll
            for (int j = 0; j < 4; ++j)
                rg[(spb + q * 4 + j) * RW + y] =
                    (unsigned short)bf16rn(__expf(-((const float*)&st[k])[j]));
        }
    };
    auto panel_flush = [&](int p) {  // ring (bf16 R) -> global f32
        const int spb = (p * 8) % RC;
#pragma unroll
        for (int k = 0; k < 4; ++k) {
            const int f = k * 64 + l, y = f >> 1, q = f & 1;
            float4 v;
#pragma unroll
            for (int j = 0; j < 4; ++j)
                ((float*)&v)[j] = __uint_as_float(
                    ((unsigned)rg[(spb + q * 4 + j) * RW + y]) << 16);
            *(float4*)(Og + (size_t)y * NC + p * 8 + q * 4) = v;
        }
    };

    for (int p = 0; p < 10; ++p) { panel_load(p); panel_write(p); }
    panel_load(10);

    const int y0 = 2 * l;  // rows y0, y0+1; packed u32 lane index = slot*64 + l
    float prevP0 = 0.f, prevP1 = 0.f;  // stored P[row, u-1] = e^{-R} * 2^E
    float h01 = 0.f;                   // prevP0 + prevP1
    float E = 0.f;                     // private per-lane scale
    float bp_r = (w == 0 && l == 0) ? 0.f : INFV;  // log R[above,u-1] (slow path)
    float r_out = INFV;                // log R[y0+1, u] for next lane (f32)
    float vab_prev = 0.f;              // cached P(R[above, u-1]) at E
    float carry = INFV;                // lane63 o1 carried one group

    // pipelined next-group state (filled at previous group's tail)
    float mgN[8];
    unsigned puN[8];
    int adN[8];

    auto prefetch_state = [&](int x) {
        const int tbx = 8 * x;
        if (w > 0 && x <= 63) {
            const int need = tbx + 8;
            int guard = 0;
            while (__hip_atomic_load(&pflag[w - 1], __ATOMIC_ACQUIRE,
                                     __HIP_MEMORY_SCOPE_WORKGROUP) < need &&
                   ++guard < (1 << 24)) {}
            const float4 m0 = *(const float4*)&mbox[(w - 1) * NC + tbx];
            const float4 m1 = *(const float4*)&mbox[(w - 1) * NC + tbx + 4];
            mgN[0] = m0.x; mgN[1] = m0.y; mgN[2] = m0.z; mgN[3] = m0.w;
            mgN[4] = m1.x; mgN[5] = m1.y; mgN[6] = m1.z; mgN[7] = m1.w;
        } else {
#pragma unroll
            for (int j = 0; j < 8; ++j) mgN[j] = INFV;
        }
        if (x >= 8 && x <= 63) {  // interior addressing
            const int v = tbx - l;   // in [1, 504]
            const int sb = v % RC;   // one mod
#pragma unroll
            for (int ph = 0; ph < 8; ++ph) {
                int a = (sb + ph) * 64 + l;          // u32 index
                if (sb + ph >= RC) a -= RC * 64;     // single wrap
                adN[ph] = a;
                puN[ph] = rgU[a];
            }
        } else {  // boundary: clamped
#pragma unroll
            for (int ph = 0; ph < 8; ++ph) {
                const int c = tbx + ph - l;
                const int cs = min(max(c, 0), NC - 1);
                adN[ph] = (cs % RC) * 64 + l;
                puN[ph] = rgU[adN[ph]];
            }
        }
    };

    for (int g = 0; g < NGRP; ++g) {
        const int h = g - GOFF * w;
        if (h < 0 || h > 71) continue;
        const int tb = 8 * h;

        if (h == 0) prefetch_state(0);  // first active group: inline fill

        // ---- group start: stage next D panel (slot freed at group h-1) ----
        if (h >= 9 && h + 1 < 64) panel_write(h + 1);  // overlaps compute below

        float mbuf[8];
        unsigned pk[8];

        if (h >= 8 && h <= 63) {
            // ================= FAST PATH (interior; all lanes valid) =======
#pragma unroll
            for (int ph = 0; ph < 8; ++ph) {
                const float up_r = wave_shr1(r_out, mgN[ph]);    // log R[y0-1,u]
                const float vab = __expf(fmaf(E, LN2F, -up_r));  // chain exp
                const float s0 = (vab_prev + vab) + prevP0;      // dab == vab_prev
                const float c0 = bf16lo(puN[ph]) * s0;
                const float s1 = h01 + c0;
                const float c1 = bf16hi(puN[ph]) * s1;
                const float o0 = fmaf(E, LN2F, -__logf(c0));
                const float o1 = fmaf(E, LN2F, -__logf(c1));
                pk[ph] = bf16rn(o0) | (bf16rn(o1) << 16);
                prevP0 = c0; prevP1 = c1; h01 = c0 + c1;
                vab_prev = vab; r_out = o1; mbuf[ph] = o1;
            }
#pragma unroll
            for (int ph = 0; ph < 8; ++ph) rgU[adN[ph]] = pk[ph];
        } else {
            // ================= SLOW PATH (boundary; R19 semantics) =========
#pragma unroll
            for (int ph = 0; ph < 8; ++ph) {
                const int u = tb + ph - l;
                const bool valid = (u >= 0) && (u < NC);
                const float up_r = wave_shr1(r_out, mgN[ph]);
                const float dab_log = bp_r;
                bp_r = up_r;
                if (valid) {
                    float dab;
                    if (u == 0) {  // cold start: adopt scale, pin boundary ~2^10
                        E = (w == 0 && l == 0) ? 0.f : floorf(up_r * L2EF) + 10.f;
                        dab = __expf(fmaf(E, LN2F, -dab_log));
                    } else {
                        dab = vab_prev;
                    }
                    const float vab = __expf(fmaf(E, LN2F, -up_r));
                    const float s0 = (dab + vab) + prevP0;
                    const float c0 = bf16lo(puN[ph]) * s0;
                    const float s1 = h01 + c0;
                    const float c1 = bf16hi(puN[ph]) * s1;
                    const float o0 = fmaf(E, LN2F, -__logf(c0));
                    const float o1 = fmaf(E, LN2F, -__logf(c1));
                    pk[ph] = bf16rn(o0) | (bf16rn(o1) << 16);
                    prevP0 = c0; prevP1 = c1; h01 = c0 + c1;
                    vab_prev = vab; r_out = o1; mbuf[ph] = o1;
                } else {
                    mbuf[ph] = INFV;
                }
            }
#pragma unroll
            for (int ph = 0; ph < 8; ++ph) {
                const int u = tb + ph - l;
                if (u >= 0 && u < NC) rgU[adN[ph]] = pk[ph];
            }
        }

        // ---- group end: mailbox write + publish (log domain, f32) ----
        if (w < 3) {
            if (h >= 8 && l == 63) {  // chunk h-8 = cols tb-64..tb-57
                *(float4*)&mbox[w * NC + tb - 64] =
                    make_float4(carry, mbuf[0], mbuf[1], mbuf[2]);
                *(float4*)&mbox[w * NC + tb - 60] =
                    make_float4(mbuf[3], mbuf[4], mbuf[5], mbuf[6]);
            }
            carry = mbuf[7];
            if (h >= 8 && l == 0) {
                __hip_atomic_store(&pflag[w], tb - 56, __ATOMIC_RELEASE,
                                   __HIP_MEMORY_SCOPE_WORKGROUP);
            }
        }

        // ---- group end: renorm (pin stored prevP0 ~2^10; log r_out immune) --
        {
            const int ex = (int)((__float_as_uint(prevP0) >> 23) & 0xffu);
            if (ex != 0) {
                const int sh = 137 - ex;
                const float f = __uint_as_float((unsigned)(sh + 127) << 23);
                E += (float)sh;
                prevP0 *= f; prevP1 *= f; h01 *= f; vab_prev *= f;
            }
        }

        // ---- group end: flush finished panel; issue next global load ----
        if (h >= 8) panel_flush(h - 8);
        if (h + 2 >= 11 && h + 2 < 64) panel_load(h + 2);

        // ---- group end: prefetch next group's inputs (writes long done) ----
        if (h < 71) prefetch_state(h + 1);
    }
}

extern "C" void kernel_launch(void* const* d_in, const int* in_sizes, int n_in,
                              void* d_out, int out_size, void* d_ws, size_t ws_size,
                              hipStream_t stream) {
    const float* D = (const float*)d_in[0];
    float* out = (float*)d_out;
    const int B = in_sizes[0] / (512 * 512);
    sdtw17<<<B, 256, 0, stream>>>(D, out);
}